// Round 6
// baseline (689.354 us; speedup 1.0000x reference)
//
#include <hip/hip_runtime.h>

// HypergraphConv: out = LN( (H diag(1/d_e) H^T x) / d_v @ W_node + x @ W_res )
//
// ROUND-6 = MEASUREMENT ROUND (replication probe).
// Identical to round-5 except gemmA and gemmB are launched 3x each (both are
// pure/idempotent). dur_us = R + 3(A+B) where round-5 dur 397 = R + (A+B),
// so A+B = (dur_us - 397)/2. This isolates the aggregation-GEMM cost, which
// five rounds of counters could not show (top-5 is always the harness's
// 1.6 GB workspace-poison fills at ~225 us each).
//
// Workspace (bytes), no aliasing:
//   WT       bf16 512x512      @ 0          (524,288)
//   Hb       u64  80x20480     @ 524,288    (13,107,200)  [mw][n]
//   HTb      u64  320x5120     @ 13,631,488 (13,107,200)  [nw][m]
//   inv_de   f32  5120         @ 26,738,688 (20,480)
//   inv_dv   f32  20480        @ 26,759,168 (81,920)
//   xpb      img  2560x256x16B @ 26,841,088 (10,485,760)
//   partialA f32  8x256x5120   @ 37,326,848 (41,943,040)
//   t2p      img  640x256x16B  @ 79,269,888 (2,621,440)
//   T3       bf16 20000x256    @ 81,891,328 (10,240,000)   total ~92 MB

#define N_NODES 20000
#define M_EDGES 5000
#define MPAD    5120
#define NPAD    20480
#define NW      320
#define MW      80
#define DIN     256
#define DOUT    512
#define SPLITS  8

typedef short bf16x8 __attribute__((ext_vector_type(8)));
typedef float f32x4 __attribute__((ext_vector_type(4)));
typedef unsigned long long u64;

#define MFMA16(A, B, C) __builtin_amdgcn_mfma_f32_16x16x32_bf16((A), (B), (C), 0, 0, 0)

__device__ __forceinline__ unsigned short f2b(float f) {
  unsigned u = __builtin_bit_cast(unsigned, f);
  return (unsigned short)((u + 0x7FFFu + ((u >> 16) & 1u)) >> 16);  // RNE
}

__device__ __forceinline__ void stage16(const void* g, void* l) {
  __builtin_amdgcn_global_load_lds(
      (const __attribute__((address_space(1))) unsigned int*)g,
      (__attribute__((address_space(3))) unsigned int*)l, 16, 0, 0);
}

// 8 bits -> 8 bf16 {0,1}: t = b|(b<<15); pair p = ((t>>2p)&0x00010001)*0x3F80
__device__ __forceinline__ bf16x8 expand8(unsigned b) {
  union { unsigned u[4]; bf16x8 v; } r;
  const unsigned t = b | (b << 15);
  r.u[0] = (t & 0x00010001u) * 0x3F80u;
  r.u[1] = ((t >> 2) & 0x00010001u) * 0x3F80u;
  r.u[2] = ((t >> 4) & 0x00010001u) * 0x3F80u;
  r.u[3] = ((t >> 6) & 0x00010001u) * 0x3F80u;
  return r.v;
}

// ---------------------------------------------------------------- prep
__global__ __launch_bounds__(256) void prep_kernel(const float* __restrict__ Wn,
                                                   const float* __restrict__ Wr,
                                                   unsigned short* __restrict__ WT) {
  const int q = blockIdx.x * 256 + threadIdx.x;  // < 262144
  const int j = q >> 9, k = q & 511;
  const float v = (k < 256) ? Wn[(size_t)k * 512 + j] : Wr[(size_t)(k - 256) * 512 + j];
  WT[(size_t)j * 512 + k] = f2b(v);
}

// ---------------------------------------------------------------- xt: x -> xpb frag image [n8][j] x 8 bf16
__global__ __launch_bounds__(256) void xt_kernel(const float* __restrict__ x,
                                                 unsigned short* __restrict__ xpb) {
  const int j = threadIdx.x;       // 0..255
  const int n8 = blockIdx.x;       // 0..2559
  union { unsigned u[4]; bf16x8 v; } o;
#pragma unroll
  for (int p = 0; p < 4; ++p) {
    const int n = n8 * 8 + 2 * p;
    const float v0 = (n < N_NODES) ? x[(size_t)n * DIN + j] : 0.f;
    const float v1 = (n + 1 < N_NODES) ? x[(size_t)(n + 1) * DIN + j] : 0.f;
    o.u[p] = (unsigned)f2b(v0) | ((unsigned)f2b(v1) << 16);
  }
  *(bf16x8*)(xpb + ((size_t)n8 * 256 + j) * 8) = o.v;
}

// ---------------------------------------------------------------- pack: H f32 -> bitmasks, both orientations
__global__ __launch_bounds__(256) void pack_kernel(const float* __restrict__ H,
                                                   u64* __restrict__ Hb,
                                                   u64* __restrict__ HTb) {
  const int t = threadIdx.x;
  const int w = t >> 6, l = t & 63;
  const int nb = blockIdx.x;   // 0..319
  const int mb = blockIdx.y;   // 0..19
  const int m = mb * 256 + w * 64 + l;
  const bool mv = m < M_EDGES;
  unsigned lo = 0, hi = 0;
  u64 myword = 0;
#pragma unroll 8
  for (int k = 0; k < 64; ++k) {
    const int n = nb * 64 + k;
    float v = 0.f;
    if (mv && n < N_NODES) v = H[(size_t)n * M_EDGES + m];
    const bool p = (v != 0.f);
    const u64 mask = __ballot(p);
    if (l == k) myword = mask;
    if (k < 32) lo |= (p ? 1u : 0u) << k;
    else        hi |= (p ? 1u : 0u) << (k - 32);
  }
  Hb[(size_t)(mb * 4 + w) * NPAD + nb * 64 + l] = myword;       // [mw][n]
  HTb[(size_t)nb * MPAD + m] = ((u64)hi << 32) | lo;            // [nw][m]
}

// ---------------------------------------------------------------- deg
__global__ __launch_bounds__(256) void deg_kernel(const u64* __restrict__ Hb,
                                                  const u64* __restrict__ HTb,
                                                  float* __restrict__ inv_de,
                                                  float* __restrict__ inv_dv) {
  const int g = blockIdx.x * 256 + threadIdx.x;
  if (g < MPAD) {
    int c = 0;
    for (int nw = 0; nw < NW; ++nw) c += __popcll(HTb[(size_t)nw * MPAD + g]);
    inv_de[g] = 1.f / fmaxf((float)c, 1.f);
  } else if (g < MPAD + NPAD) {
    const int n = g - MPAD;
    int c = 0;
#pragma unroll
    for (int mw = 0; mw < MW; ++mw) c += __popcll(Hb[(size_t)mw * NPAD + n]);
    inv_dv[n] = 1.f / fmaxf((float)c, 1.f);
  }
}

// ---------------------------------------------------------------- gemmA: partialA[s] = x^T @ H
// 4 waves, block tile 64j x 256m (wave-private 64m), K-split 8 (40 steps of 64n).
__global__ __launch_bounds__(256) void gemmA_kernel(const unsigned short* __restrict__ xpb,
                                                    const u64* __restrict__ HTb,
                                                    float* __restrict__ partial) {
  __shared__ char lds[2][8192];
  const int t = threadIdx.x;
  const int w = t >> 6, l = t & 63;
  const int lr = l & 15, lg = l >> 4;
  const int shl8 = lg * 8;
  const int wgid = blockIdx.x;
  const int mchunk = wgid >> 5;
  const int sj = wgid & 31;
  const int s = sj >> 2, jb = sj & 3;
  const int m0 = mchunk * 256 + w * 64;
  const int j0 = jb * 64;

  f32x4 acc[4][4] = {};
  const u64* bbase = HTb + (size_t)(s * 40) * MPAD + m0 + lr;
  const char* xb = (const char*)xpb;
  const int n8b = s * 320;
  const int sj0 = j0 + w * 16 + lr;   // staging column (fr = w)

  u64 b00, b01, b02, b03, b10, b11, b12, b13;

#define GA_LOADB(S, st_) do {                                                  \
    const u64* bp_ = bbase + (size_t)(st_) * MPAD;                             \
    b##S##0 = bp_[0]; b##S##1 = bp_[16]; b##S##2 = bp_[32]; b##S##3 = bp_[48]; \
  } while (0)

#define GA_STAGE(buf, st_) do {                                                \
    const size_t s0_ = ((size_t)(n8b + (st_) * 8 + lg) * 256 + sj0) * 16;      \
    const size_t s1_ = ((size_t)(n8b + (st_) * 8 + 4 + lg) * 256 + sj0) * 16;  \
    stage16(xb + s0_, &lds[buf][w * 1024 + l * 16]);                           \
    stage16(xb + s1_, &lds[buf][(4 + w) * 1024 + l * 16]);                     \
  } while (0)

#define GA_JG(jg, BW) do {                                                     \
    const unsigned wlo_ = (unsigned)(BW), whi_ = (unsigned)((BW) >> 32);       \
    const bf16x8 e0_ = expand8((wlo_ >> shl8) & 255u);                         \
    const bf16x8 e1_ = expand8((whi_ >> shl8) & 255u);                         \
    acc[0][jg] = MFMA16(A00_, e0_, acc[0][jg]);                                \
    acc[1][jg] = MFMA16(A10_, e0_, acc[1][jg]);                                \
    acc[2][jg] = MFMA16(A20_, e0_, acc[2][jg]);                                \
    acc[3][jg] = MFMA16(A30_, e0_, acc[3][jg]);                                \
    acc[0][jg] = MFMA16(A01_, e1_, acc[0][jg]);                                \
    acc[1][jg] = MFMA16(A11_, e1_, acc[1][jg]);                                \
    acc[2][jg] = MFMA16(A21_, e1_, acc[2][jg]);                                \
    acc[3][jg] = MFMA16(A31_, e1_, acc[3][jg]);                                \
  } while (0)

#define GA_COMP(buf, S) do {                                                   \
    const char* L_ = &lds[buf][0];                                             \
    const bf16x8 A00_ = *(const bf16x8*)(L_ + l * 16 + 0);                     \
    const bf16x8 A10_ = *(const bf16x8*)(L_ + l * 16 + 1024);                  \
    const bf16x8 A20_ = *(const bf16x8*)(L_ + l * 16 + 2048);                  \
    const bf16x8 A30_ = *(const bf16x8*)(L_ + l * 16 + 3072);                  \
    const bf16x8 A01_ = *(const bf16x8*)(L_ + l * 16 + 4096);                  \
    const bf16x8 A11_ = *(const bf16x8*)(L_ + l * 16 + 5120);                  \
    const bf16x8 A21_ = *(const bf16x8*)(L_ + l * 16 + 6144);                  \
    const bf16x8 A31_ = *(const bf16x8*)(L_ + l * 16 + 7168);                  \
    GA_JG(0, b##S##0); GA_JG(1, b##S##1); GA_JG(2, b##S##2); GA_JG(3, b##S##3);\
  } while (0)

  GA_LOADB(0, 0);
  GA_STAGE(0, 0);
  for (int st = 0; st < 40; st += 2) {
    const int n1 = (st + 1 < 40) ? st + 1 : 39;
    GA_LOADB(1, n1); GA_STAGE(1, n1);
    asm volatile("s_waitcnt vmcnt(6)" ::: "memory");
    __builtin_amdgcn_s_barrier();
    GA_COMP(0, 0);
    __builtin_amdgcn_s_barrier();
    const int n2 = (st + 2 < 40) ? st + 2 : 39;
    GA_LOADB(0, n2); GA_STAGE(0, n2);
    asm volatile("s_waitcnt vmcnt(6)" ::: "memory");
    __builtin_amdgcn_s_barrier();
    GA_COMP(1, 1);
    __builtin_amdgcn_s_barrier();
  }
#undef GA_LOADB
#undef GA_STAGE
#undef GA_JG
#undef GA_COMP

  float* pp = partial + (size_t)s * (DIN * MPAD);
#pragma unroll
  for (int fr = 0; fr < 4; ++fr)
#pragma unroll
    for (int r = 0; r < 4; ++r) {
      const int j = j0 + fr * 16 + lg * 4 + r;
#pragma unroll
      for (int jg = 0; jg < 4; ++jg)
        pp[(size_t)j * MPAD + m0 + jg * 16 + lr] = acc[fr][jg][r];
    }
}

// ---------------------------------------------------------------- reduceA: coalesced (m on threads)
__global__ __launch_bounds__(256) void reduceA_kernel(const float* __restrict__ partial,
                                                      const float* __restrict__ inv_de,
                                                      unsigned short* __restrict__ t2p) {
  const int t = threadIdx.x;
  const int m = blockIdx.x * 256 + t;       // 0..5119
  const int jc = blockIdx.y * 16;           // 16 j per block
  const float e = inv_de[m];
  unsigned short* ob = t2p + ((size_t)(m >> 3) * 256) * 8 + (m & 7);
  for (int jj = 0; jj < 16; ++jj) {
    const int j = jc + jj;
    const float* p = partial + (size_t)j * MPAD + m;
    float s = 0.f;
#pragma unroll
    for (int sp = 0; sp < SPLITS; ++sp) s += p[(size_t)sp * (DIN * MPAD)];
    ob[(size_t)j * 8] = f2b(s * e);
  }
}

// ---------------------------------------------------------------- gemmB: T3 = bf16((H @ T2)/d_v)
__global__ __launch_bounds__(256) void gemmB_kernel(const unsigned short* __restrict__ t2p,
                                                    const u64* __restrict__ Hb,
                                                    const float* __restrict__ inv_dv,
                                                    unsigned short* __restrict__ T3) {
  __shared__ char lds[2][8192];
  const int t = threadIdx.x;
  const int w = t >> 6, l = t & 63;
  const int lr = l & 15, lg = l >> 4;
  const int shl8 = lg * 8;
  const int wgid = blockIdx.x;
  const int nchunk = wgid >> 2;
  const int jb = wgid & 3;
  const int n0 = nchunk * 256 + w * 64;
  const int j0 = jb * 64;

  f32x4 acc[4][4] = {};
  const u64* abase = Hb + n0 + lr;
  const char* tb = (const char*)t2p;
  const int sj0 = j0 + w * 16 + lr;   // staging column (jg = w)

  u64 a00, a01, a02, a03, a10, a11, a12, a13;

#define GB_LOADA(S, st_) do {                                                  \
    const u64* ap_ = abase + (size_t)(st_) * NPAD;                             \
    a##S##0 = ap_[0]; a##S##1 = ap_[16]; a##S##2 = ap_[32]; a##S##3 = ap_[48]; \
  } while (0)

#define GB_STAGE(buf, st_) do {                                                \
    const size_t s0_ = ((size_t)((st_) * 8 + lg) * 256 + sj0) * 16;            \
    const size_t s1_ = ((size_t)((st_) * 8 + 4 + lg) * 256 + sj0) * 16;        \
    stage16(tb + s0_, &lds[buf][w * 1024 + l * 16]);                           \
    stage16(tb + s1_, &lds[buf][(4 + w) * 1024 + l * 16]);                     \
  } while (0)

#define GB_FR(fr, AW) do {                                                     \
    const unsigned wlo_ = (unsigned)(AW), whi_ = (unsigned)((AW) >> 32);       \
    const bf16x8 e0_ = expand8((wlo_ >> shl8) & 255u);                         \
    const bf16x8 e1_ = expand8((whi_ >> shl8) & 255u);                         \
    acc[fr][0] = MFMA16(e0_, B00_, acc[fr][0]);                                \
    acc[fr][1] = MFMA16(e0_, B10_, acc[fr][1]);                                \
    acc[fr][2] = MFMA16(e0_, B20_, acc[fr][2]);                                \
    acc[fr][3] = MFMA16(e0_, B30_, acc[fr][3]);                                \
    acc[fr][0] = MFMA16(e1_, B01_, acc[fr][0]);                                \
    acc[fr][1] = MFMA16(e1_, B11_, acc[fr][1]);                                \
    acc[fr][2] = MFMA16(e1_, B21_, acc[fr][2]);                                \
    acc[fr][3] = MFMA16(e1_, B31_, acc[fr][3]);                                \
  } while (0)

#define GB_COMP(buf, S) do {                                                   \
    const char* L_ = &lds[buf][0];                                             \
    const bf16x8 B00_ = *(const bf16x8*)(L_ + l * 16 + 0);                     \
    const bf16x8 B10_ = *(const bf16x8*)(L_ + l * 16 + 1024);                  \
    const bf16x8 B20_ = *(const bf16x8*)(L_ + l * 16 + 2048);                  \
    const bf16x8 B30_ = *(const bf16x8*)(L_ + l * 16 + 3072);                  \
    const bf16x8 B01_ = *(const bf16x8*)(L_ + l * 16 + 4096);                  \
    const bf16x8 B11_ = *(const bf16x8*)(L_ + l * 16 + 5120);                  \
    const bf16x8 B21_ = *(const bf16x8*)(L_ + l * 16 + 6144);                  \
    const bf16x8 B31_ = *(const bf16x8*)(L_ + l * 16 + 7168);                  \
    GB_FR(0, a##S##0); GB_FR(1, a##S##1); GB_FR(2, a##S##2); GB_FR(3, a##S##3);\
  } while (0)

  GB_LOADA(0, 0);
  GB_STAGE(0, 0);
  for (int st = 0; st < 80; st += 2) {
    const int n1 = (st + 1 < 80) ? st + 1 : 79;
    GB_LOADA(1, n1); GB_STAGE(1, n1);
    asm volatile("s_waitcnt vmcnt(6)" ::: "memory");
    __builtin_amdgcn_s_barrier();
    GB_COMP(0, 0);
    __builtin_amdgcn_s_barrier();
    const int n2 = (st + 2 < 80) ? st + 2 : 79;
    GB_LOADA(0, n2); GB_STAGE(0, n2);
    asm volatile("s_waitcnt vmcnt(6)" ::: "memory");
    __builtin_amdgcn_s_barrier();
    GB_COMP(1, 1);
    __builtin_amdgcn_s_barrier();
  }
#undef GB_LOADA
#undef GB_STAGE
#undef GB_FR
#undef GB_COMP

#pragma unroll
  for (int fr = 0; fr < 4; ++fr) {
    const f32x4 dv = *(const f32x4*)(inv_dv + n0 + fr * 16 + lg * 4);
#pragma unroll
    for (int r = 0; r < 4; ++r) {
      const int n = n0 + fr * 16 + lg * 4 + r;
      if (n < N_NODES) {
#pragma unroll
        for (int jg = 0; jg < 4; ++jg)
          T3[(size_t)n * DIN + j0 + jg * 16 + lr] = f2b(acc[fr][jg][r] * dv[r]);
      }
    }
  }
}

// ---------------------------------------------------------------- gemmC: out = [T3 | x] @ WT_cat (f32)
__global__ __launch_bounds__(512) void gemmC_kernel(const float* __restrict__ x,
                                                    const unsigned short* __restrict__ T3,
                                                    const unsigned short* __restrict__ WT,
                                                    float* __restrict__ out) {
  __shared__ unsigned short As[128 * 64];
  __shared__ unsigned short Bsh[128 * 64];
  const int t = threadIdx.x;
  const int n0 = blockIdx.x * 128;
  const int j0 = blockIdx.y * 128;
  const int w = t >> 6, l = t & 63;
  const int wr = w >> 2, wc = w & 3;
  const int lr = l & 15, lg = l >> 4;
  f32x4 acc[4][2];
#pragma unroll
  for (int i = 0; i < 4; ++i)
#pragma unroll
    for (int jq = 0; jq < 2; ++jq) acc[i][jq] = (f32x4){0.f, 0.f, 0.f, 0.f};
  const int sr = t >> 3, sk8 = t & 7;

  for (int st = 0; st < 8; ++st) {
    __syncthreads();
#pragma unroll
    for (int p = 0; p < 2; ++p) {
      const int node = sr + p * 64;
      const int gn = n0 + node;
      bf16x8 pk;
      if (st < 4) {
        if (gn < N_NODES)
          pk = *(const bf16x8*)(T3 + (size_t)gn * DIN + st * 64 + sk8 * 8);
        else {
#pragma unroll
          for (int jq = 0; jq < 8; ++jq) pk[jq] = 0;
        }
      } else {
        if (gn < N_NODES) {
          const float4* p4 = (const float4*)(x + (size_t)gn * DIN + (st - 4) * 64 + sk8 * 8);
          const float4 q0 = p4[0], q1 = p4[1];
          pk[0] = (short)f2b(q0.x); pk[1] = (short)f2b(q0.y); pk[2] = (short)f2b(q0.z); pk[3] = (short)f2b(q0.w);
          pk[4] = (short)f2b(q1.x); pk[5] = (short)f2b(q1.y); pk[6] = (short)f2b(q1.z); pk[7] = (short)f2b(q1.w);
        } else {
#pragma unroll
          for (int jq = 0; jq < 8; ++jq) pk[jq] = 0;
        }
      }
      *(bf16x8*)((char*)As + node * 128 + ((sk8 * 16) ^ ((node & 7) << 4))) = pk;
    }
#pragma unroll
    for (int p = 0; p < 2; ++p) {
      const int j = sr + p * 64;
      const bf16x8 pk = *(const bf16x8*)(WT + (size_t)(j0 + j) * 512 + st * 64 + sk8 * 8);
      *(bf16x8*)((char*)Bsh + j * 128 + ((sk8 * 16) ^ ((j & 7) << 4))) = pk;
    }
    __syncthreads();
#pragma unroll
    for (int ks = 0; ks < 2; ++ks) {
      const int kb = ks * 64 + 16 * lg;
      bf16x8 bf[2];
#pragma unroll
      for (int fc = 0; fc < 2; ++fc) {
        const int row = wc * 32 + fc * 16 + lr;
        bf[fc] = *(const bf16x8*)((const char*)Bsh + row * 128 + (kb ^ ((row & 7) << 4)));
      }
#pragma unroll
      for (int fr = 0; fr < 4; ++fr) {
        const int row = wr * 64 + fr * 16 + lr;
        const bf16x8 af = *(const bf16x8*)((const char*)As + row * 128 + (kb ^ ((row & 7) << 4)));
#pragma unroll
        for (int fc = 0; fc < 2; ++fc)
          acc[fr][fc] = __builtin_amdgcn_mfma_f32_16x16x32_bf16(af, bf[fc], acc[fr][fc], 0, 0, 0);
      }
    }
  }
#pragma unroll
  for (int fr = 0; fr < 4; ++fr)
#pragma unroll
    for (int fc = 0; fc < 2; ++fc) {
      const int col = j0 + wc * 32 + fc * 16 + lr;
#pragma unroll
      for (int r = 0; r < 4; ++r) {
        const int row = n0 + wr * 64 + fr * 16 + 4 * lg + r;
        if (row < N_NODES) out[(size_t)row * DOUT + col] = acc[fr][fc][r];
      }
    }
}

// ---------------------------------------------------------------- LayerNorm (in place on out)
__global__ __launch_bounds__(256) void ln_kernel(float* __restrict__ out,
                                                 const float* __restrict__ gamma,
                                                 const float* __restrict__ beta) {
  const int row = blockIdx.x * 4 + (threadIdx.x >> 6);
  const int l = threadIdx.x & 63;
  float* p = out + (size_t)row * DOUT;
  float4 va = *(const float4*)(p + 4 * l);
  float4 vb = *(const float4*)(p + 256 + 4 * l);
  float s = va.x + va.y + va.z + va.w + vb.x + vb.y + vb.z + vb.w;
  float s2 = va.x * va.x + va.y * va.y + va.z * va.z + va.w * va.w +
             vb.x * vb.x + vb.y * vb.y + vb.z * vb.z + vb.w * vb.w;
#pragma unroll
  for (int m = 1; m < 64; m <<= 1) { s += __shfl_xor(s, m, 64); s2 += __shfl_xor(s2, m, 64); }
  const float mu = s * (1.f / DOUT);
  const float rs = rsqrtf(s2 * (1.f / DOUT) - mu * mu + 1e-5f);
  const float4 g0 = *(const float4*)(gamma + 4 * l);
  const float4 g1 = *(const float4*)(gamma + 256 + 4 * l);
  const float4 b0 = *(const float4*)(beta + 4 * l);
  const float4 b1 = *(const float4*)(beta + 256 + 4 * l);
  va.x = (va.x - mu) * rs * g0.x + b0.x;  va.y = (va.y - mu) * rs * g0.y + b0.y;
  va.z = (va.z - mu) * rs * g0.z + b0.z;  va.w = (va.w - mu) * rs * g0.w + b0.w;
  vb.x = (vb.x - mu) * rs * g1.x + b1.x;  vb.y = (vb.y - mu) * rs * g1.y + b1.y;
  vb.z = (vb.z - mu) * rs * g1.z + b1.z;  vb.w = (vb.w - mu) * rs * g1.w + b1.w;
  *(float4*)(p + 4 * l) = va;
  *(float4*)(p + 256 + 4 * l) = vb;
}

// ----------------------------------------------------------------
extern "C" void kernel_launch(void* const* d_in, const int* in_sizes, int n_in,
                              void* d_out, int out_size, void* d_ws, size_t ws_size,
                              hipStream_t stream) {
  (void)in_sizes; (void)n_in; (void)out_size; (void)ws_size;
  const float* x = (const float*)d_in[0];
  const float* H = (const float*)d_in[1];
  const float* Wn = (const float*)d_in[2];
  const float* Wr = (const float*)d_in[3];
  const float* gamma = (const float*)d_in[4];
  const float* beta = (const float*)d_in[5];
  float* out = (float*)d_out;
  char* ws = (char*)d_ws;

  unsigned short* WT  = (unsigned short*)(ws + 0);
  u64* Hb             = (u64*)(ws + 524288);
  u64* HTb            = (u64*)(ws + 13631488);
  float* inv_de       = (float*)(ws + 26738688);
  float* inv_dv       = (float*)(ws + 26759168);
  unsigned short* xpb = (unsigned short*)(ws + 26841088);
  float* partial      = (float*)(ws + 37326848);
  unsigned short* t2p = (unsigned short*)(ws + 79269888);
  unsigned short* T3  = (unsigned short*)(ws + 81891328);

  prep_kernel<<<dim3(1024), dim3(256), 0, stream>>>(Wn, Wr, WT);
  xt_kernel<<<dim3(2560), dim3(256), 0, stream>>>(x, xpb);
  pack_kernel<<<dim3(320, 20), dim3(256), 0, stream>>>(H, Hb, HTb);
  deg_kernel<<<dim3(100), dim3(256), 0, stream>>>(Hb, HTb, inv_de, inv_dv);
  // --- replication probe: gemmA x3, gemmB x3 (idempotent; measures A+B) ---
  gemmA_kernel<<<dim3(640), dim3(256), 0, stream>>>(xpb, HTb, partial);
  gemmA_kernel<<<dim3(640), dim3(256), 0, stream>>>(xpb, HTb, partial);
  gemmA_kernel<<<dim3(640), dim3(256), 0, stream>>>(xpb, HTb, partial);
  reduceA_kernel<<<dim3(20, 16), dim3(256), 0, stream>>>(partial, inv_de, t2p);
  gemmB_kernel<<<dim3(316), dim3(256), 0, stream>>>(t2p, Hb, inv_dv, T3);
  gemmB_kernel<<<dim3(316), dim3(256), 0, stream>>>(t2p, Hb, inv_dv, T3);
  gemmB_kernel<<<dim3(316), dim3(256), 0, stream>>>(t2p, Hb, inv_dv, T3);
  gemmC_kernel<<<dim3(157, 4), dim3(512), 0, stream>>>(x, T3, WT, out);
  ln_kernel<<<dim3(5000), dim3(256), 0, stream>>>(out, gamma, beta);
}

// Round 7
// 337.116 us; speedup vs baseline: 2.0449x; 2.0449x over previous
//
#include <hip/hip_runtime.h>

// HypergraphConv: out = LN( (H diag(1/d_e) H^T x) / d_v @ W_node + x @ W_res )
//
// Round-7: (a) pack rewritten ROW-STREAMING (float4 row chunks; HTb words
// accumulated in per-thread registers over 64 rows; Hb row-words via 16-lane
// shfl_xor OR-reduce) -- the old pack column-walked H in 256B/20KB-stride
// chunks (~2 TB/s effective, ~180 us). (b) aggregation GEMM occupancy 2x:
// gemmA split-K 16 (grid 1280), gemmB split-K 2 w/ f32 partials (grid 640)
// + reduceB (applies 1/d_v). Probe r6: A+B was 146 us (latency-bound,
// gemmB at 1.23 blocks/CU).
//
// Workspace (bytes):
//   WT       bf16 512x512       @ 0           (524,288)
//   Hb       u64  80x20480      @ 524,288     (13,107,200)  [mw][n]
//   HTb      u64  320x5120      @ 13,631,488  (13,107,200)  [nw][m]
//   inv_de   f32  5120          @ 26,738,688  (20,480)
//   inv_dv   f32  20480         @ 26,759,168  (81,920)
//   xpb      img  2560x256x16B  @ 26,841,088  (10,485,760)
//   partialA f32  16x256x5120   @ 37,326,848  (83,886,080)
//   t2p      img  640x256x16B   @ 121,212,928 (2,621,440)
//   partialB f32  2x20480x256   @ 123,834,368 (41,943,040)
//   T3       bf16 20000x256     @ 165,777,408 (10,240,000)   total ~176 MB

#define N_NODES 20000
#define M_EDGES 5000
#define MPAD    5120
#define NPAD    20480
#define NW      320
#define MW      80
#define DIN     256
#define DOUT    512
#define SPLITS  16

typedef short bf16x4 __attribute__((ext_vector_type(4)));
typedef short bf16x8 __attribute__((ext_vector_type(8)));
typedef float f32x4 __attribute__((ext_vector_type(4)));
typedef unsigned long long u64;

#define MFMA16(A, B, C) __builtin_amdgcn_mfma_f32_16x16x32_bf16((A), (B), (C), 0, 0, 0)

__device__ __forceinline__ unsigned short f2b(float f) {
  unsigned u = __builtin_bit_cast(unsigned, f);
  return (unsigned short)((u + 0x7FFFu + ((u >> 16) & 1u)) >> 16);  // RNE
}

__device__ __forceinline__ void stage16(const void* g, void* l) {
  __builtin_amdgcn_global_load_lds(
      (const __attribute__((address_space(1))) unsigned int*)g,
      (__attribute__((address_space(3))) unsigned int*)l, 16, 0, 0);
}

// 8 bits -> 8 bf16 {0,1}: t = b|(b<<15); pair p = ((t>>2p)&0x00010001)*0x3F80
__device__ __forceinline__ bf16x8 expand8(unsigned b) {
  union { unsigned u[4]; bf16x8 v; } r;
  const unsigned t = b | (b << 15);
  r.u[0] = (t & 0x00010001u) * 0x3F80u;
  r.u[1] = ((t >> 2) & 0x00010001u) * 0x3F80u;
  r.u[2] = ((t >> 4) & 0x00010001u) * 0x3F80u;
  r.u[3] = ((t >> 6) & 0x00010001u) * 0x3F80u;
  return r.v;
}

// ---------------------------------------------------------------- prep
__global__ __launch_bounds__(256) void prep_kernel(const float* __restrict__ Wn,
                                                   const float* __restrict__ Wr,
                                                   unsigned short* __restrict__ WT) {
  const int q = blockIdx.x * 256 + threadIdx.x;  // < 262144
  const int j = q >> 9, k = q & 511;
  const float v = (k < 256) ? Wn[(size_t)k * 512 + j] : Wr[(size_t)(k - 256) * 512 + j];
  WT[(size_t)j * 512 + k] = f2b(v);
}

// ---------------------------------------------------------------- xt: x -> xpb frag image [n8][j] x 8 bf16
__global__ __launch_bounds__(256) void xt_kernel(const float* __restrict__ x,
                                                 unsigned short* __restrict__ xpb) {
  const int j = threadIdx.x;       // 0..255
  const int n8 = blockIdx.x;       // 0..2559
  union { unsigned u[4]; bf16x8 v; } o;
#pragma unroll
  for (int p = 0; p < 4; ++p) {
    const int n = n8 * 8 + 2 * p;
    const float v0 = (n < N_NODES) ? x[(size_t)n * DIN + j] : 0.f;
    const float v1 = (n + 1 < N_NODES) ? x[(size_t)(n + 1) * DIN + j] : 0.f;
    o.u[p] = (unsigned)f2b(v0) | ((unsigned)f2b(v1) << 16);
  }
  *(bf16x8*)(xpb + ((size_t)n8 * 256 + j) * 8) = o.v;
}

// ---------------------------------------------------------------- pack v2: ROW-STREAMING
// Block: 64 rows (n0..n0+63) x 1024 cols (m0..m0+1023). Thread t owns 4 fixed
// cols mc..mc+3; float4 row loads (4KB contiguous per block-row).
// HTb words: per-thread u64 accumulation over rows. Hb words: per-row 16-lane
// shfl_xor OR-reduce of nib<<(4*(l&15)).
__global__ __launch_bounds__(256) void pack_kernel(const float* __restrict__ H,
                                                   u64* __restrict__ Hb,
                                                   u64* __restrict__ HTb) {
  const int t = threadIdx.x;
  const int l = t & 63;
  const int w = t >> 6;
  const int g = blockIdx.x;        // 0..319 (n-group)
  const int h = blockIdx.y;        // 0..4   (m-group)
  const int n0 = g * 64;
  const int mc = h * 1024 + 4 * t; // this thread's 4 columns
  u64 ht0 = 0, ht1 = 0, ht2 = 0, ht3 = 0;
  const int mw = h * 16 + w * 4 + (l >> 4);      // global m-word 0..79
  u64* hbp = Hb + (size_t)mw * NPAD + n0;
  const bool hbw = ((l & 15) == 0);
  const int shn = 4 * (l & 15);

  for (int r = 0; r < 64; ++r) {
    const int n = n0 + r;
    unsigned nib = 0;
    if (n < N_NODES) {
      if (mc + 3 < M_EDGES) {
        const float4 v = *(const float4*)(H + (size_t)n * M_EDGES + mc);
        nib = (v.x != 0.f ? 1u : 0u) | (v.y != 0.f ? 2u : 0u) |
              (v.z != 0.f ? 4u : 0u) | (v.w != 0.f ? 8u : 0u);
      } else if (mc < M_EDGES) {
#pragma unroll
        for (int j = 0; j < 4; ++j)
          if (mc + j < M_EDGES)
            nib |= (H[(size_t)n * M_EDGES + mc + j] != 0.f ? 1u : 0u) << j;
      }
    }
    ht0 |= (u64)(nib & 1u) << r;
    ht1 |= (u64)((nib >> 1) & 1u) << r;
    ht2 |= (u64)((nib >> 2) & 1u) << r;
    ht3 |= (u64)((nib >> 3) & 1u) << r;
    u64 val = (u64)nib << shn;
    val |= __shfl_xor(val, 1, 64);
    val |= __shfl_xor(val, 2, 64);
    val |= __shfl_xor(val, 4, 64);
    val |= __shfl_xor(val, 8, 64);
    if (hbw) hbp[r] = val;
  }
  u64* htp = HTb + (size_t)g * MPAD + mc;
  htp[0] = ht0; htp[1] = ht1; htp[2] = ht2; htp[3] = ht3;
}

// ---------------------------------------------------------------- deg
__global__ __launch_bounds__(256) void deg_kernel(const u64* __restrict__ Hb,
                                                  const u64* __restrict__ HTb,
                                                  float* __restrict__ inv_de,
                                                  float* __restrict__ inv_dv) {
  const int g = blockIdx.x * 256 + threadIdx.x;
  if (g < MPAD) {
    int c = 0;
    for (int nw = 0; nw < NW; ++nw) c += __popcll(HTb[(size_t)nw * MPAD + g]);
    inv_de[g] = 1.f / fmaxf((float)c, 1.f);
  } else if (g < MPAD + NPAD) {
    const int n = g - MPAD;
    int c = 0;
#pragma unroll
    for (int mw = 0; mw < MW; ++mw) c += __popcll(Hb[(size_t)mw * NPAD + n]);
    inv_dv[n] = 1.f / fmaxf((float)c, 1.f);
  }
}

// ---------------------------------------------------------------- gemmA: partialA[s] = x^T @ H
// 4 waves, block tile 64j x 256m (wave-private 64m), K-split 16 (20 steps of 64n).
// grid 1280 1-D: mchunk = wgid>>6; sj = wgid&63 (s=sj>>2, jb=sj&3).
__global__ __launch_bounds__(256) void gemmA_kernel(const unsigned short* __restrict__ xpb,
                                                    const u64* __restrict__ HTb,
                                                    float* __restrict__ partial) {
  __shared__ char lds[2][8192];
  const int t = threadIdx.x;
  const int w = t >> 6, l = t & 63;
  const int lr = l & 15, lg = l >> 4;
  const int shl8 = lg * 8;
  const int wgid = blockIdx.x;
  const int mchunk = wgid >> 6;
  const int sj = wgid & 63;
  const int s = sj >> 2, jb = sj & 3;
  const int m0 = mchunk * 256 + w * 64;
  const int j0 = jb * 64;

  f32x4 acc[4][4] = {};
  const u64* bbase = HTb + (size_t)(s * 20) * MPAD + m0 + lr;
  const char* xb = (const char*)xpb;
  const int n8b = s * 160;
  const int sj0 = j0 + w * 16 + lr;

  u64 b00, b01, b02, b03, b10, b11, b12, b13;

#define GA_LOADB(S, st_) do {                                                  \
    const u64* bp_ = bbase + (size_t)(st_) * MPAD;                             \
    b##S##0 = bp_[0]; b##S##1 = bp_[16]; b##S##2 = bp_[32]; b##S##3 = bp_[48]; \
  } while (0)

#define GA_STAGE(buf, st_) do {                                                \
    const size_t s0_ = ((size_t)(n8b + (st_) * 8 + lg) * 256 + sj0) * 16;      \
    const size_t s1_ = ((size_t)(n8b + (st_) * 8 + 4 + lg) * 256 + sj0) * 16;  \
    stage16(xb + s0_, &lds[buf][w * 1024 + l * 16]);                           \
    stage16(xb + s1_, &lds[buf][(4 + w) * 1024 + l * 16]);                     \
  } while (0)

#define GA_JG(jg, BW) do {                                                     \
    const unsigned wlo_ = (unsigned)(BW), whi_ = (unsigned)((BW) >> 32);       \
    const bf16x8 e0_ = expand8((wlo_ >> shl8) & 255u);                         \
    const bf16x8 e1_ = expand8((whi_ >> shl8) & 255u);                         \
    acc[0][jg] = MFMA16(A00_, e0_, acc[0][jg]);                                \
    acc[1][jg] = MFMA16(A10_, e0_, acc[1][jg]);                                \
    acc[2][jg] = MFMA16(A20_, e0_, acc[2][jg]);                                \
    acc[3][jg] = MFMA16(A30_, e0_, acc[3][jg]);                                \
    acc[0][jg] = MFMA16(A01_, e1_, acc[0][jg]);                                \
    acc[1][jg] = MFMA16(A11_, e1_, acc[1][jg]);                                \
    acc[2][jg] = MFMA16(A21_, e1_, acc[2][jg]);                                \
    acc[3][jg] = MFMA16(A31_, e1_, acc[3][jg]);                                \
  } while (0)

#define GA_COMP(buf, S) do {                                                   \
    const char* L_ = &lds[buf][0];                                             \
    const bf16x8 A00_ = *(const bf16x8*)(L_ + l * 16 + 0);                     \
    const bf16x8 A10_ = *(const bf16x8*)(L_ + l * 16 + 1024);                  \
    const bf16x8 A20_ = *(const bf16x8*)(L_ + l * 16 + 2048);                  \
    const bf16x8 A30_ = *(const bf16x8*)(L_ + l * 16 + 3072);                  \
    const bf16x8 A01_ = *(const bf16x8*)(L_ + l * 16 + 4096);                  \
    const bf16x8 A11_ = *(const bf16x8*)(L_ + l * 16 + 5120);                  \
    const bf16x8 A21_ = *(const bf16x8*)(L_ + l * 16 + 6144);                  \
    const bf16x8 A31_ = *(const bf16x8*)(L_ + l * 16 + 7168);                  \
    GA_JG(0, b##S##0); GA_JG(1, b##S##1); GA_JG(2, b##S##2); GA_JG(3, b##S##3);\
  } while (0)

  GA_LOADB(0, 0);
  GA_STAGE(0, 0);
  for (int st = 0; st < 20; st += 2) {
    const int n1 = (st + 1 < 20) ? st + 1 : 19;
    GA_LOADB(1, n1); GA_STAGE(1, n1);
    asm volatile("s_waitcnt vmcnt(6)" ::: "memory");
    __builtin_amdgcn_s_barrier();
    GA_COMP(0, 0);
    __builtin_amdgcn_s_barrier();
    const int n2 = (st + 2 < 20) ? st + 2 : 19;
    GA_LOADB(0, n2); GA_STAGE(0, n2);
    asm volatile("s_waitcnt vmcnt(6)" ::: "memory");
    __builtin_amdgcn_s_barrier();
    GA_COMP(1, 1);
    __builtin_amdgcn_s_barrier();
  }
#undef GA_LOADB
#undef GA_STAGE
#undef GA_JG
#undef GA_COMP

  float* pp = partial + (size_t)s * (DIN * MPAD);
#pragma unroll
  for (int fr = 0; fr < 4; ++fr)
#pragma unroll
    for (int r = 0; r < 4; ++r) {
      const int j = j0 + fr * 16 + lg * 4 + r;
#pragma unroll
      for (int jg = 0; jg < 4; ++jg)
        pp[(size_t)j * MPAD + m0 + jg * 16 + lr] = acc[fr][jg][r];
    }
}

// ---------------------------------------------------------------- reduceA: coalesced (m on threads)
__global__ __launch_bounds__(256) void reduceA_kernel(const float* __restrict__ partial,
                                                      const float* __restrict__ inv_de,
                                                      unsigned short* __restrict__ t2p) {
  const int t = threadIdx.x;
  const int m = blockIdx.x * 256 + t;       // 0..5119
  const int jc = blockIdx.y * 16;           // 16 j per block
  const float e = inv_de[m];
  unsigned short* ob = t2p + ((size_t)(m >> 3) * 256) * 8 + (m & 7);
  for (int jj = 0; jj < 16; ++jj) {
    const int j = jc + jj;
    const float* p = partial + (size_t)j * MPAD + m;
    float s = 0.f;
#pragma unroll
    for (int sp = 0; sp < SPLITS; ++sp) s += p[(size_t)sp * (DIN * MPAD)];
    ob[(size_t)j * 8] = f2b(s * e);
  }
}

// ---------------------------------------------------------------- gemmB: partialB[s] = H @ T2 (f32)
// 4 waves, block tile 256n (wave-private 64) x 64j, K-split 2 (40 steps of 64m).
// grid 640 1-D: nchunk = wgid>>3; sj = wgid&7 (s=sj>>2, jb=sj&3).
__global__ __launch_bounds__(256) void gemmB_kernel(const unsigned short* __restrict__ t2p,
                                                    const u64* __restrict__ Hb,
                                                    float* __restrict__ partialB) {
  __shared__ char lds[2][8192];
  const int t = threadIdx.x;
  const int w = t >> 6, l = t & 63;
  const int lr = l & 15, lg = l >> 4;
  const int shl8 = lg * 8;
  const int wgid = blockIdx.x;
  const int nchunk = wgid >> 3;
  const int sj = wgid & 7;
  const int s = sj >> 2, jb = sj & 3;
  const int n0 = nchunk * 256 + w * 64;
  const int j0 = jb * 64;

  f32x4 acc[4][4] = {};
  const u64* abase = Hb + (size_t)(s * 40) * NPAD + n0 + lr;
  const char* tb = (const char*)t2p;
  const int m8b = s * 320;
  const int sj0 = j0 + w * 16 + lr;

  u64 a00, a01, a02, a03, a10, a11, a12, a13;

#define GB_LOADA(S, st_) do {                                                  \
    const u64* ap_ = abase + (size_t)(st_) * NPAD;                             \
    a##S##0 = ap_[0]; a##S##1 = ap_[16]; a##S##2 = ap_[32]; a##S##3 = ap_[48]; \
  } while (0)

#define GB_STAGE(buf, st_) do {                                                \
    const size_t s0_ = ((size_t)(m8b + (st_) * 8 + lg) * 256 + sj0) * 16;      \
    const size_t s1_ = ((size_t)(m8b + (st_) * 8 + 4 + lg) * 256 + sj0) * 16;  \
    stage16(tb + s0_, &lds[buf][w * 1024 + l * 16]);                           \
    stage16(tb + s1_, &lds[buf][(4 + w) * 1024 + l * 16]);                     \
  } while (0)

#define GB_FR(fr, AW) do {                                                     \
    const unsigned wlo_ = (unsigned)(AW), whi_ = (unsigned)((AW) >> 32);       \
    const bf16x8 e0_ = expand8((wlo_ >> shl8) & 255u);                         \
    const bf16x8 e1_ = expand8((whi_ >> shl8) & 255u);                         \
    acc[fr][0] = MFMA16(e0_, B00_, acc[fr][0]);                                \
    acc[fr][1] = MFMA16(e0_, B10_, acc[fr][1]);                                \
    acc[fr][2] = MFMA16(e0_, B20_, acc[fr][2]);                                \
    acc[fr][3] = MFMA16(e0_, B30_, acc[fr][3]);                                \
    acc[fr][0] = MFMA16(e1_, B01_, acc[fr][0]);                                \
    acc[fr][1] = MFMA16(e1_, B11_, acc[fr][1]);                                \
    acc[fr][2] = MFMA16(e1_, B21_, acc[fr][2]);                                \
    acc[fr][3] = MFMA16(e1_, B31_, acc[fr][3]);                                \
  } while (0)

#define GB_COMP(buf, S) do {                                                   \
    const char* L_ = &lds[buf][0];                                             \
    const bf16x8 B00_ = *(const bf16x8*)(L_ + l * 16 + 0);                     \
    const bf16x8 B10_ = *(const bf16x8*)(L_ + l * 16 + 1024);                  \
    const bf16x8 B20_ = *(const bf16x8*)(L_ + l * 16 + 2048);                  \
    const bf16x8 B30_ = *(const bf16x8*)(L_ + l * 16 + 3072);                  \
    const bf16x8 B01_ = *(const bf16x8*)(L_ + l * 16 + 4096);                  \
    const bf16x8 B11_ = *(const bf16x8*)(L_ + l * 16 + 5120);                  \
    const bf16x8 B21_ = *(const bf16x8*)(L_ + l * 16 + 6144);                  \
    const bf16x8 B31_ = *(const bf16x8*)(L_ + l * 16 + 7168);                  \
    GB_FR(0, a##S##0); GB_FR(1, a##S##1); GB_FR(2, a##S##2); GB_FR(3, a##S##3);\
  } while (0)

  GB_LOADA(0, 0);
  GB_STAGE(0, 0);
  for (int st = 0; st < 40; st += 2) {
    const int n1 = (st + 1 < 40) ? st + 1 : 39;
    GB_LOADA(1, n1); GB_STAGE(1, n1);
    asm volatile("s_waitcnt vmcnt(6)" ::: "memory");
    __builtin_amdgcn_s_barrier();
    GB_COMP(0, 0);
    __builtin_amdgcn_s_barrier();
    const int n2 = (st + 2 < 40) ? st + 2 : 39;
    GB_LOADA(0, n2); GB_STAGE(0, n2);
    asm volatile("s_waitcnt vmcnt(6)" ::: "memory");
    __builtin_amdgcn_s_barrier();
    GB_COMP(1, 1);
    __builtin_amdgcn_s_barrier();
  }
#undef GB_LOADA
#undef GB_STAGE
#undef GB_FR
#undef GB_COMP

  float* pp = partialB + (size_t)s * ((size_t)NPAD * DIN);
#pragma unroll
  for (int fr = 0; fr < 4; ++fr) {
#pragma unroll
    for (int r = 0; r < 4; ++r) {
      const int n = n0 + fr * 16 + lg * 4 + r;
#pragma unroll
      for (int jg = 0; jg < 4; ++jg)
        pp[(size_t)n * DIN + j0 + jg * 16 + lr] = acc[fr][jg][r];
    }
  }
}

// ---------------------------------------------------------------- reduceB: T3 = bf16((p0+p1) * inv_dv)
__global__ __launch_bounds__(256) void reduceB_kernel(const float* __restrict__ partialB,
                                                      const float* __restrict__ inv_dv,
                                                      unsigned short* __restrict__ T3) {
  const size_t idx4 = (size_t)blockIdx.x * 1024 + threadIdx.x * 4;  // < 20000*256
  const f32x4 a = *(const f32x4*)(partialB + idx4);
  const f32x4 b = *(const f32x4*)(partialB + (size_t)NPAD * DIN + idx4);
  const float dv = inv_dv[idx4 >> 8];
  bf16x4 o;
#pragma unroll
  for (int i = 0; i < 4; ++i) o[i] = (short)f2b((a[i] + b[i]) * dv);
  *(bf16x4*)(T3 + idx4) = o;
}

// ---------------------------------------------------------------- gemmC: out = [T3 | x] @ WT_cat (f32)
__global__ __launch_bounds__(512) void gemmC_kernel(const float* __restrict__ x,
                                                    const unsigned short* __restrict__ T3,
                                                    const unsigned short* __restrict__ WT,
                                                    float* __restrict__ out) {
  __shared__ unsigned short As[128 * 64];
  __shared__ unsigned short Bsh[128 * 64];
  const int t = threadIdx.x;
  const int n0 = blockIdx.x * 128;
  const int j0 = blockIdx.y * 128;
  const int w = t >> 6, l = t & 63;
  const int wr = w >> 2, wc = w & 3;
  const int lr = l & 15, lg = l >> 4;
  f32x4 acc[4][2];
#pragma unroll
  for (int i = 0; i < 4; ++i)
#pragma unroll
    for (int jq = 0; jq < 2; ++jq) acc[i][jq] = (f32x4){0.f, 0.f, 0.f, 0.f};
  const int sr = t >> 3, sk8 = t & 7;

  for (int st = 0; st < 8; ++st) {
    __syncthreads();
#pragma unroll
    for (int p = 0; p < 2; ++p) {
      const int node = sr + p * 64;
      const int gn = n0 + node;
      bf16x8 pk;
      if (st < 4) {
        if (gn < N_NODES)
          pk = *(const bf16x8*)(T3 + (size_t)gn * DIN + st * 64 + sk8 * 8);
        else {
#pragma unroll
          for (int jq = 0; jq < 8; ++jq) pk[jq] = 0;
        }
      } else {
        if (gn < N_NODES) {
          const float4* p4 = (const float4*)(x + (size_t)gn * DIN + (st - 4) * 64 + sk8 * 8);
          const float4 q0 = p4[0], q1 = p4[1];
          pk[0] = (short)f2b(q0.x); pk[1] = (short)f2b(q0.y); pk[2] = (short)f2b(q0.z); pk[3] = (short)f2b(q0.w);
          pk[4] = (short)f2b(q1.x); pk[5] = (short)f2b(q1.y); pk[6] = (short)f2b(q1.z); pk[7] = (short)f2b(q1.w);
        } else {
#pragma unroll
          for (int jq = 0; jq < 8; ++jq) pk[jq] = 0;
        }
      }
      *(bf16x8*)((char*)As + node * 128 + ((sk8 * 16) ^ ((node & 7) << 4))) = pk;
    }
#pragma unroll
    for (int p = 0; p < 2; ++p) {
      const int j = sr + p * 64;
      const bf16x8 pk = *(const bf16x8*)(WT + (size_t)(j0 + j) * 512 + st * 64 + sk8 * 8);
      *(bf16x8*)((char*)Bsh + j * 128 + ((sk8 * 16) ^ ((j & 7) << 4))) = pk;
    }
    __syncthreads();
#pragma unroll
    for (int ks = 0; ks < 2; ++ks) {
      const int kb = ks * 64 + 16 * lg;
      bf16x8 bf[2];
#pragma unroll
      for (int fc = 0; fc < 2; ++fc) {
        const int row = wc * 32 + fc * 16 + lr;
        bf[fc] = *(const bf16x8*)((const char*)Bsh + row * 128 + (kb ^ ((row & 7) << 4)));
      }
#pragma unroll
      for (int fr = 0; fr < 4; ++fr) {
        const int row = wr * 64 + fr * 16 + lr;
        const bf16x8 af = *(const bf16x8*)((const char*)As + row * 128 + (kb ^ ((row & 7) << 4)));
#pragma unroll
        for (int fc = 0; fc < 2; ++fc)
          acc[fr][fc] = __builtin_amdgcn_mfma_f32_16x16x32_bf16(af, bf[fc], acc[fr][fc], 0, 0, 0);
      }
    }
  }
#pragma unroll
  for (int fr = 0; fr < 4; ++fr)
#pragma unroll
    for (int fc = 0; fc < 2; ++fc) {
      const int col = j0 + wc * 32 + fc * 16 + lr;
#pragma unroll
      for (int r = 0; r < 4; ++r) {
        const int row = n0 + wr * 64 + fr * 16 + 4 * lg + r;
        if (row < N_NODES) out[(size_t)row * DOUT + col] = acc[fr][fc][r];
      }
    }
}

// ---------------------------------------------------------------- LayerNorm (in place on out)
__global__ __launch_bounds__(256) void ln_kernel(float* __restrict__ out,
                                                 const float* __restrict__ gamma,
                                                 const float* __restrict__ beta) {
  const int row = blockIdx.x * 4 + (threadIdx.x >> 6);
  const int l = threadIdx.x & 63;
  float* p = out + (size_t)row * DOUT;
  float4 va = *(const float4*)(p + 4 * l);
  float4 vb = *(const float4*)(p + 256 + 4 * l);
  float s = va.x + va.y + va.z + va.w + vb.x + vb.y + vb.z + vb.w;
  float s2 = va.x * va.x + va.y * va.y + va.z * va.z + va.w * va.w +
             vb.x * vb.x + vb.y * vb.y + vb.z * vb.z + vb.w * vb.w;
#pragma unroll
  for (int m = 1; m < 64; m <<= 1) { s += __shfl_xor(s, m, 64); s2 += __shfl_xor(s2, m, 64); }
  const float mu = s * (1.f / DOUT);
  const float rs = rsqrtf(s2 * (1.f / DOUT) - mu * mu + 1e-5f);
  const float4 g0 = *(const float4*)(gamma + 4 * l);
  const float4 g1 = *(const float4*)(gamma + 256 + 4 * l);
  const float4 b0 = *(const float4*)(beta + 4 * l);
  const float4 b1 = *(const float4*)(beta + 256 + 4 * l);
  va.x = (va.x - mu) * rs * g0.x + b0.x;  va.y = (va.y - mu) * rs * g0.y + b0.y;
  va.z = (va.z - mu) * rs * g0.z + b0.z;  va.w = (va.w - mu) * rs * g0.w + b0.w;
  vb.x = (vb.x - mu) * rs * g1.x + b1.x;  vb.y = (vb.y - mu) * rs * g1.y + b1.y;
  vb.z = (vb.z - mu) * rs * g1.z + b1.z;  vb.w = (vb.w - mu) * rs * g1.w + b1.w;
  *(float4*)(p + 4 * l) = va;
  *(float4*)(p + 256 + 4 * l) = vb;
}

// ----------------------------------------------------------------
extern "C" void kernel_launch(void* const* d_in, const int* in_sizes, int n_in,
                              void* d_out, int out_size, void* d_ws, size_t ws_size,
                              hipStream_t stream) {
  (void)in_sizes; (void)n_in; (void)out_size; (void)ws_size;
  const float* x = (const float*)d_in[0];
  const float* H = (const float*)d_in[1];
  const float* Wn = (const float*)d_in[2];
  const float* Wr = (const float*)d_in[3];
  const float* gamma = (const float*)d_in[4];
  const float* beta = (const float*)d_in[5];
  float* out = (float*)d_out;
  char* ws = (char*)d_ws;

  unsigned short* WT  = (unsigned short*)(ws + 0);
  u64* Hb             = (u64*)(ws + 524288);
  u64* HTb            = (u64*)(ws + 13631488);
  float* inv_de       = (float*)(ws + 26738688);
  float* inv_dv       = (float*)(ws + 26759168);
  unsigned short* xpb = (unsigned short*)(ws + 26841088);
  float* partialA     = (float*)(ws + 37326848);
  unsigned short* t2p = (unsigned short*)(ws + 121212928);
  float* partialB     = (float*)(ws + 123834368);
  unsigned short* T3  = (unsigned short*)(ws + 165777408);

  prep_kernel<<<dim3(1024), dim3(256), 0, stream>>>(Wn, Wr, WT);
  xt_kernel<<<dim3(2560), dim3(256), 0, stream>>>(x, xpb);
  pack_kernel<<<dim3(320, 5), dim3(256), 0, stream>>>(H, Hb, HTb);
  deg_kernel<<<dim3(100), dim3(256), 0, stream>>>(Hb, HTb, inv_de, inv_dv);
  gemmA_kernel<<<dim3(1280), dim3(256), 0, stream>>>(xpb, HTb, partialA);
  reduceA_kernel<<<dim3(20, 16), dim3(256), 0, stream>>>(partialA, inv_de, t2p);
  gemmB_kernel<<<dim3(640), dim3(256), 0, stream>>>(t2p, Hb, partialB);
  reduceB_kernel<<<dim3(5000), dim3(256), 0, stream>>>(partialB, inv_dv, T3);
  gemmC_kernel<<<dim3(157, 4), dim3(512), 0, stream>>>(x, T3, WT, out);
  ln_kernel<<<dim3(5000), dim3(256), 0, stream>>>(out, gamma, beta);
}